// Round 5
// baseline (765.607 us; speedup 1.0000x reference)
//
#include <hip/hip_runtime.h>
#include <hip/hip_bf16.h>

// Problem geometry (from reference):
//   vision_x:            [B=4, T_VIS=32, D=4096] f32   d_in[0]
//   weight:              [VOCAB=32000, D=4096]  f32    d_in[1]
//   figure_token_weight: [2, D=4096]            f32    d_in[2]
//   text_input:          [B=4, T=2048]          int    d_in[3]
//   out:                 [B, T, D]              f32
//
// MEASUREMENT ROUND: pass 0 is the verified round-4 kernel unchanged.
// Passes 1..3 are salted gather clones writing to d_ws — they exist only
// to measure the true per-pass device time via the dur_us delta
// (dur_us ~= overhead + 4K instead of overhead + K). Correctness is
// unaffected: d_out is written only by pass 0.

#define VOCAB   32000
#define D       4096
#define D4      (D / 4)       // 1024 16-byte vectors per row
#define T_VIS   32
#define TOK_T   2048          // tokens per batch
#define NTOK    (4 * TOK_T)   // 8192 total tokens
#define OUT_BYTES ((size_t)NTOK * D * 4)   // 134 MB

typedef float f32x4 __attribute__((ext_vector_type(4)));

__global__ __launch_bounds__(256) void embed_gather_kernel(
    const f32x4* __restrict__ vision,   // [B, T_VIS, D]
    const f32x4* __restrict__ weight,   // [VOCAB, D]
    const f32x4* __restrict__ fig,      // [2, D]
    const int*   __restrict__ idx,      // [B, T]
    f32x4*       __restrict__ out)      // [B, T, D]
{
    const int token = blockIdx.x;        // 0 .. NTOK-1
    const int b     = token >> 11;       // token / TOK_T (TOK_T = 2048)
    const int id    = idx[token];        // block-uniform -> scalar load

    const f32x4* src;
    if (id < VOCAB) {
        src = weight + (size_t)id * D4;
    } else if (id < VOCAB + 2) {
        src = fig + (size_t)(id - VOCAB) * D4;
    } else {
        src = vision + ((size_t)b * T_VIS + (size_t)(id - VOCAB - 2)) * D4;
    }

    f32x4* dst = out + (size_t)token * D4;

    #pragma unroll
    for (int i = 0; i < D4; i += 256) {
        f32x4 v = src[i + threadIdx.x];
        __builtin_nontemporal_store(v, &dst[i + threadIdx.x]);
    }
}

// Timing probe: same gather shape, salted row ids (mostly cold reads),
// writes to scratch. Never touches d_out.
__global__ __launch_bounds__(256) void embed_gather_probe_kernel(
    const f32x4* __restrict__ weight,   // [VOCAB, D]
    const int*   __restrict__ idx,      // [B, T]
    f32x4*       __restrict__ dst,      // scratch, [NTOK, D]
    unsigned     salt)
{
    const int token = blockIdx.x;
    const unsigned id = ((unsigned)idx[token] + salt) % VOCAB;  // always a weight row
    const f32x4* src = weight + (size_t)id * D4;
    f32x4* d = dst + (size_t)token * D4;

    #pragma unroll
    for (int i = 0; i < D4; i += 256) {
        f32x4 v = src[i + threadIdx.x];
        __builtin_nontemporal_store(v, &d[i + threadIdx.x]);
    }
}

extern "C" void kernel_launch(void* const* d_in, const int* in_sizes, int n_in,
                              void* d_out, int out_size, void* d_ws, size_t ws_size,
                              hipStream_t stream) {
    const f32x4* vision = (const f32x4*)d_in[0];
    const f32x4* weight = (const f32x4*)d_in[1];
    const f32x4* fig    = (const f32x4*)d_in[2];
    const int*   idx    = (const int*)d_in[3];
    f32x4*       out    = (f32x4*)d_out;

    // Pass 0: the real (verified) gather.
    embed_gather_kernel<<<NTOK, 256, 0, stream>>>(vision, weight, fig, idx, out);

    // Passes 1..3: timing probes into scratch (only if ws is big enough).
    if (ws_size >= 3 * OUT_BYTES) {
        f32x4* ws = (f32x4*)d_ws;
        for (unsigned p = 1; p <= 3; ++p) {
            embed_gather_probe_kernel<<<NTOK, 256, 0, stream>>>(
                weight, idx, ws + (size_t)(p - 1) * NTOK * D4, p * 7919u);
        }
    }
}